// Round 12
// baseline (83650.250 us; speedup 1.0000x reference)
//
#include <hip/hip_runtime.h>
#include <math.h>

#define BB 256   // batch
#define TT 512   // encoder seq len
#define DD 64    // state dim
#define HH 512   // hidden dim
#define FF 32    // fc_seq_len
#define NTH 512  // threads per wg (thread t owns hidden col j=t, all 3 gates)

__device__ __forceinline__ float sigmoidf_(float x) { return 1.0f / (1.0f + __expf(-x)); }

// ======================= batch-stationary single kernel =======================
// 64 wgs, each owns 4 batch rows and runs the ENTIRE network (512 encoder GRU
// steps + 32 fc_predicts + 31 decoder GRU steps) with only __syncthreads().
// No cross-wg dependency exists: batch rows are independent; each wg holds its
// h (and fc activations) in LDS. Weights stream from L2/L3 each step in
// transposed [k][gate][j] layout so lane j's load is coalesced; h/x/a operands
// are LDS broadcasts (address uniform across lanes -> conflict-free).

// transposed weights in d_ws:
//  WtI[(k*3+g)*HH + j] = W_ih[(g*HH+j)*DD + k]   (k<64)
//  WtH[(k*3+g)*HH + j] = W_hh[(g*HH+j)*HH + k]   (k<512)
//  F1T[k*HH + j]       = fc1_w[j*HH + k]
//  F2T[k*DD + d]       = fc2_w[d*HH + k]
#define N_WTI (DD * 3 * HH)
#define N_WTH (HH * 3 * HH)
#define N_F1T (HH * HH)
#define N_F2T (HH * DD)

__global__ void prep_transpose(const float* __restrict__ W_ih,
                               const float* __restrict__ W_hh,
                               const float* __restrict__ fc1_w,
                               const float* __restrict__ fc2_w,
                               float* __restrict__ WtI, float* __restrict__ WtH,
                               float* __restrict__ F1T, float* __restrict__ F2T) {
    const int total = N_WTI + N_WTH + N_F1T + N_F2T;
    for (int i = blockIdx.x * blockDim.x + threadIdx.x; i < total;
         i += gridDim.x * blockDim.x) {
        if (i < N_WTI) {
            const int k = i / (3 * HH), r = i % (3 * HH), g = r / HH, j = r % HH;
            WtI[i] = W_ih[(g * HH + j) * DD + k];
        } else if (i < N_WTI + N_WTH) {
            const int i2 = i - N_WTI;
            const int k = i2 / (3 * HH), r = i2 % (3 * HH), g = r / HH, j = r % HH;
            WtH[i2] = W_hh[(g * HH + j) * HH + k];
        } else if (i < N_WTI + N_WTH + N_F1T) {
            const int i3 = i - N_WTI - N_WTH;
            const int k = i3 / HH, j = i3 % HH;
            F1T[i3] = fc1_w[j * HH + k];
        } else {
            const int i4 = i - N_WTI - N_WTH - N_F1T;
            const int k = i4 / DD, d = i4 % DD;
            F2T[i4] = fc2_w[d * HH + k];
        }
    }
}

// 4 k-columns of the 3 gate GEMMs: 12 coalesced weight loads, 4 LDS-broadcast
// float4 reads, 48 FMAs into 16 independent accumulators.
#define GATE1(Q, COMP, K, WSRC, AN)                                        \
    {                                                                      \
        const float wr_ = WSRC[((K) * 3 + 0) * HH + j];                    \
        const float wz_ = WSRC[((K) * 3 + 1) * HH + j];                    \
        const float wn_ = WSRC[((K) * 3 + 2) * HH + j];                    \
        _Pragma("unroll")                                                  \
        for (int b = 0; b < 4; ++b) {                                      \
            ar[b] = fmaf(Q[b].COMP, wr_, ar[b]);                           \
            az[b] = fmaf(Q[b].COMP, wz_, az[b]);                           \
            AN[b] = fmaf(Q[b].COMP, wn_, AN[b]);                           \
        }                                                                  \
    }

__global__ void __launch_bounds__(NTH, 1) gru_all(
    const float* __restrict__ state_seq,
    const float* __restrict__ WtI, const float* __restrict__ WtH,
    const float* __restrict__ b_ih, const float* __restrict__ b_hh,
    const float* __restrict__ F1T, const float* __restrict__ fc1_b,
    const float* __restrict__ F2T, const float* __restrict__ fc2_b,
    float* __restrict__ out_s, float* __restrict__ out_h)
{
    __shared__ float hl[2][4][HH];     // double-buffered hidden state (16 KB)
    __shared__ float xs[4][DD];        // current x (or predicted s)
    __shared__ float al[4][HH + 4];    // fc1 activations, stride 516 (bank-spread)

    const int tid = threadIdx.x;       // j = tid
    const int j = tid;
    const int b0 = blockIdx.x * 4;

    const float br  = b_ih[j] + b_hh[j];
    const float bz  = b_ih[HH + j] + b_hh[HH + j];
    const float bin = b_ih[2 * HH + j];
    const float bhn = b_hh[2 * HH + j];
    const float fb1 = fc1_b[j];

    #pragma unroll
    for (int b = 0; b < 4; ++b) hl[0][b][tid] = 0.f;   // h0 = 0
    __syncthreads();

    int cur = 0;
    for (int t = 0; t < TT + FF - 1; ++t) {
        const bool enc = (t < TT);
        if (enc) {   // stage x_t from state_seq; decoder reuses xs (= s)
            if (tid < 256) {
                const int b = tid >> 6, k = tid & 63;
                xs[b][k] = state_seq[((size_t)(b0 + b) * TT + t) * DD + k];
            }
            __syncthreads();
        }

        // ---- GRU gates: r,z merged x+h; n split (anx = i_n, anh = h_n) ----
        float ar[4] = {0,0,0,0}, az[4] = {0,0,0,0};
        float anx[4] = {0,0,0,0}, anh[4] = {0,0,0,0};

        for (int k4 = 0; k4 < DD / 4; ++k4) {          // x part (W_ih)
            float4 q[4];
            #pragma unroll
            for (int b = 0; b < 4; ++b) q[b] = *(const float4*)&xs[b][k4 * 4];
            GATE1(q, x, k4 * 4 + 0, WtI, anx)
            GATE1(q, y, k4 * 4 + 1, WtI, anx)
            GATE1(q, z, k4 * 4 + 2, WtI, anx)
            GATE1(q, w, k4 * 4 + 3, WtI, anx)
        }
        for (int k4 = 0; k4 < HH / 4; ++k4) {          // h part (W_hh)
            float4 q[4];
            #pragma unroll
            for (int b = 0; b < 4; ++b) q[b] = *(const float4*)&hl[cur][b][k4 * 4];
            GATE1(q, x, k4 * 4 + 0, WtH, anh)
            GATE1(q, y, k4 * 4 + 1, WtH, anh)
            GATE1(q, z, k4 * 4 + 2, WtH, anh)
            GATE1(q, w, k4 * 4 + 3, WtH, anh)
        }

        // ---- epilogue: n = tanh(i_n + r*h_n); h' = (1-z)n + z h ----
        #pragma unroll
        for (int b = 0; b < 4; ++b) {
            const float r = sigmoidf_(ar[b] + br);
            const float z = sigmoidf_(az[b] + bz);
            const float hold = hl[cur][b][j];
            const float n = tanhf(anx[b] + bin + r * (anh[b] + bhn));
            const float hn = (1.f - z) * n + z * hold;
            hl[cur ^ 1][b][j] = hn;
            if (!enc || t == TT - 1) {                 // h_seq[f]: f=0 for h_n
                const int f = enc ? 0 : (t - TT + 1);
                out_h[((size_t)(b0 + b) * FF + f) * HH + j] = hn;
            }
        }
        __syncthreads();
        cur ^= 1;

        // ---- fc_predict after the encoder's last h and each decoder h ----
        if (t >= TT - 1) {
            const int td = t - (TT - 1);               // 0..31
            // fc1 + ReLU: thread j computes a[b][j]
            float ac[4] = {0,0,0,0};
            for (int k4 = 0; k4 < HH / 4; ++k4) {
                float4 q[4];
                #pragma unroll
                for (int b = 0; b < 4; ++b) q[b] = *(const float4*)&hl[cur][b][k4 * 4];
                const float w0 = F1T[(k4 * 4 + 0) * HH + j];
                const float w1 = F1T[(k4 * 4 + 1) * HH + j];
                const float w2 = F1T[(k4 * 4 + 2) * HH + j];
                const float w3 = F1T[(k4 * 4 + 3) * HH + j];
                #pragma unroll
                for (int b = 0; b < 4; ++b) {
                    ac[b] = fmaf(q[b].x, w0, ac[b]);
                    ac[b] = fmaf(q[b].y, w1, ac[b]);
                    ac[b] = fmaf(q[b].z, w2, ac[b]);
                    ac[b] = fmaf(q[b].w, w3, ac[b]);
                }
            }
            #pragma unroll
            for (int b = 0; b < 4; ++b) al[b][j] = fmaxf(ac[b] + fb1, 0.f);
            __syncthreads();

            // fc2: threads 0..255, (b = tid>>6, d = tid&63)
            if (tid < 256) {
                const int b = tid >> 6, d = tid & 63;
                float s = fc2_b[d];
                for (int k4 = 0; k4 < HH / 4; ++k4) {
                    const float4 aq = *(const float4*)&al[b][k4 * 4];
                    s = fmaf(aq.x, F2T[(k4 * 4 + 0) * DD + d], s);
                    s = fmaf(aq.y, F2T[(k4 * 4 + 1) * DD + d], s);
                    s = fmaf(aq.z, F2T[(k4 * 4 + 2) * DD + d], s);
                    s = fmaf(aq.w, F2T[(k4 * 4 + 3) * DD + d], s);
                }
                xs[b][d] = s;                          // next GRU input
                out_s[((size_t)(b0 + b) * FF + td) * DD + d] = s;
            }
            __syncthreads();
        }
    }
}

// ======================= fallback: round-11 path (17.7 ms, verified) =========
__device__ __forceinline__ void stage_issue_wj(float4* v, const float* __restrict__ src,
                                               int rs, int col0, int b0, int tid) {
    #pragma unroll
    for (int u = 0; u < 4; ++u) {
        const int idx = u * 256 + tid, r = idx >> 4, c4 = idx & 15;
        v[u] = *(const float4*)&src[(b0 + r) * rs + col0 + c4 * 4];
    }
}
__device__ __forceinline__ void stage_commit_wj(float4 (*buf)[16], const float4* v, int tid) {
    #pragma unroll
    for (int u = 0; u < 4; ++u) {
        const int idx = u * 256 + tid, r = idx >> 4, c4 = idx & 15;
        buf[r][c4 ^ (r & 15)] = v[u];
    }
}
__device__ __forceinline__ void compute_chunk_wj(
    const float4 (*buf)[16], int lane,
    const float* __restrict__ wr_row, const float* __restrict__ wz_row,
    const float* __restrict__ wn_row, int kb0,
    float& ar, float& az, float& an) {
    #pragma unroll
    for (int blk = 0; blk < 4; ++blk) {
        float4 hq[4];
        #pragma unroll
        for (int q = 0; q < 4; ++q) hq[q] = buf[lane][(blk * 4 + q) ^ (lane & 15)];
        const float4* wr4 = (const float4*)&wr_row[kb0 + blk * 16];
        const float4* wz4 = (const float4*)&wz_row[kb0 + blk * 16];
        const float4* wn4 = (const float4*)&wn_row[kb0 + blk * 16];
        #pragma unroll
        for (int q = 0; q < 4; ++q) {
            const float4 w0 = wr4[q], w1 = wz4[q], w2 = wn4[q];
            ar = fmaf(hq[q].x, w0.x, ar); ar = fmaf(hq[q].y, w0.y, ar);
            ar = fmaf(hq[q].z, w0.z, ar); ar = fmaf(hq[q].w, w0.w, ar);
            az = fmaf(hq[q].x, w1.x, az); az = fmaf(hq[q].y, w1.y, az);
            az = fmaf(hq[q].z, w1.z, az); az = fmaf(hq[q].w, w1.w, az);
            an = fmaf(hq[q].x, w2.x, an); an = fmaf(hq[q].y, w2.y, an);
            an = fmaf(hq[q].z, w2.z, an); an = fmaf(hq[q].w, w2.w, an);
        }
    }
}
__global__ void __launch_bounds__(256, 2) gru_step_wj(
    const float* __restrict__ x, int xs_, const float* __restrict__ h,
    const float* __restrict__ W_ih, const float* __restrict__ W_hh,
    const float* __restrict__ b_ih, const float* __restrict__ b_hh,
    float* __restrict__ hnew, float* __restrict__ h2, int h2s) {
    __shared__ float4 buf[2][64][16];
    const int tid = threadIdx.x;
    const int lane = tid & 63, wv = tid >> 6;
    const int b0 = blockIdx.y * 64;
    const int j = __builtin_amdgcn_readfirstlane(blockIdx.x * 4 + wv);
    const float* wr_ih = &W_ih[(0 * HH + j) * DD];
    const float* wz_ih = &W_ih[(1 * HH + j) * DD];
    const float* wn_ih = &W_ih[(2 * HH + j) * DD];
    const float* wr_hh = &W_hh[(0 * HH + j) * HH];
    const float* wz_hh = &W_hh[(1 * HH + j) * HH];
    const float* wn_hh = &W_hh[(2 * HH + j) * HH];
    float ar = 0.f, az = 0.f, ain = 0.f, ahn = 0.f;
    float4 v[4];
    stage_issue_wj(v, x, xs_, 0, b0, tid);
    stage_commit_wj(buf[0], v, tid);
    __syncthreads();
    if (h) stage_issue_wj(v, h, HH, 0, b0, tid);
    compute_chunk_wj(buf[0], lane, wr_ih, wz_ih, wn_ih, 0, ar, az, ain);
    if (h) stage_commit_wj(buf[1], v, tid);
    __syncthreads();
    if (h) {
        for (int c = 1; c < 9; ++c) {
            if (c < 8) stage_issue_wj(v, h, HH, c * 64, b0, tid);
            compute_chunk_wj(buf[c & 1], lane, wr_hh, wz_hh, wn_hh,
                             (c - 1) * 64, ar, az, ahn);
            if (c < 8) stage_commit_wj(buf[(c + 1) & 1], v, tid);
            __syncthreads();
        }
    }
    const float br  = b_ih[j] + b_hh[j];
    const float bz  = b_ih[HH + j] + b_hh[HH + j];
    const float bin = b_ih[2 * HH + j];
    const float bhn = b_hh[2 * HH + j];
    const int bg = b0 + lane;
    const float r = sigmoidf_(ar + br);
    const float z = sigmoidf_(az + bz);
    const float hold = h ? h[bg * HH + j] : 0.f;
    const float n = tanhf(ain + bin + r * (ahn + bhn));
    const float hn = (1.f - z) * n + z * hold;
    hnew[bg * HH + j] = hn;
    if (h2) h2[bg * h2s + j] = hn;
}
struct SmemOld { float hs[16][34]; float ws[96][34]; };
__global__ __launch_bounds__(256) void fc1_relu(
    const float* __restrict__ h, const float* __restrict__ wsrc,
    const float* __restrict__ bias, float* __restrict__ out) {
    __shared__ SmemOld sm;
    float (*hs)[34] = sm.hs; float (*ws)[34] = sm.ws;
    const int tid = threadIdx.x;
    const int jj = tid & 31, bb = tid >> 5;
    const int j0 = blockIdx.x * 32, b0 = blockIdx.y * 16;
    float a0 = 0.f, a1 = 0.f;
    for (int kt = 0; kt < HH; kt += 32) {
        { const int r = tid >> 4, c2 = (tid & 15) * 2;
          *(float2*)&hs[r][c2] = *(const float2*)&h[(b0 + r) * HH + kt + c2]; }
        #pragma unroll
        for (int i = 0; i < 2; ++i) {
            const int idx = i * 256 + tid, r = idx >> 4, c2 = (idx & 15) * 2;
            *(float2*)&ws[r][c2] = *(const float2*)&wsrc[(j0 + r) * HH + kt + c2];
        }
        __syncthreads();
        #pragma unroll
        for (int k = 0; k < 32; k += 2) {
            const float2 h0 = *(const float2*)&hs[bb][k];
            const float2 h1 = *(const float2*)&hs[bb + 8][k];
            const float2 w0 = *(const float2*)&ws[jj][k];
            a0 = fmaf(h0.x, w0.x, a0); a0 = fmaf(h0.y, w0.y, a0);
            a1 = fmaf(h1.x, w0.x, a1); a1 = fmaf(h1.y, w0.y, a1);
        }
        __syncthreads();
    }
    const float b = bias[j0 + jj];
    out[(b0 + bb) * HH + j0 + jj]     = fmaxf(a0 + b, 0.f);
    out[(b0 + bb + 8) * HH + j0 + jj] = fmaxf(a1 + b, 0.f);
}
__global__ __launch_bounds__(256) void fc2_out(
    const float* __restrict__ a, const float* __restrict__ wsrc,
    const float* __restrict__ bias, float* __restrict__ s_buf,
    float* __restrict__ s_out, int s_stride) {
    __shared__ SmemOld sm;
    float (*as)[34] = sm.hs; float (*ws)[34] = sm.ws;
    const int tid = threadIdx.x;
    const int d = tid & 63, bb = tid >> 6;
    const int b0 = blockIdx.x * 4;
    float acc = 0.f;
    for (int kt = 0; kt < HH; kt += 32) {
        if (tid < 64) { const int r = tid >> 4, c2 = (tid & 15) * 2;
            *(float2*)&as[r][c2] = *(const float2*)&a[(b0 + r) * HH + kt + c2]; }
        #pragma unroll
        for (int i = 0; i < 4; ++i) {
            const int idx = i * 256 + tid, r = idx >> 4, c2 = (idx & 15) * 2;
            *(float2*)&ws[r][c2] = *(const float2*)&wsrc[r * HH + kt + c2];
        }
        __syncthreads();
        #pragma unroll
        for (int k = 0; k < 32; k += 2) {
            const float2 av = *(const float2*)&as[bb][k];
            const float2 wv = *(const float2*)&ws[d][k];
            acc = fmaf(av.x, wv.x, acc); acc = fmaf(av.y, wv.y, acc);
        }
        __syncthreads();
    }
    const float v = acc + bias[d];
    s_buf[(b0 + bb) * DD + d] = v;
    s_out[(b0 + bb) * s_stride + d] = v;
}

extern "C" void kernel_launch(void* const* d_in, const int* in_sizes, int n_in,
                              void* d_out, int out_size, void* d_ws, size_t ws_size,
                              hipStream_t stream) {
    const float* state_seq = (const float*)d_in[0];  // [256,512,64]
    const float* W_ih  = (const float*)d_in[1];      // [1536,64]
    const float* W_hh  = (const float*)d_in[2];      // [1536,512]
    const float* b_ih  = (const float*)d_in[3];
    const float* b_hh  = (const float*)d_in[4];
    const float* fc1_w = (const float*)d_in[5];      // [512,512]
    const float* fc1_b = (const float*)d_in[6];
    const float* fc2_w = (const float*)d_in[7];      // [64,512]
    const float* fc2_b = (const float*)d_in[8];

    float* out_s = (float*)d_out;                    // [256, 32, 64]
    float* out_h = out_s + BB * FF * DD;             // [256, 32, 512]

    const size_t needT = (size_t)(N_WTI + N_WTH + N_F1T + N_F2T) * 4;  // 4.72 MB

    if (ws_size >= needT) {
        float* WtI = (float*)d_ws;
        float* WtH = WtI + N_WTI;
        float* F1T = WtH + N_WTH;
        float* F2T = F1T + N_F1T;
        prep_transpose<<<dim3(1024), dim3(256), 0, stream>>>(
            W_ih, W_hh, fc1_w, fc2_w, WtI, WtH, F1T, F2T);
        gru_all<<<dim3(BB / 4), dim3(NTH), 0, stream>>>(
            state_seq, WtI, WtH, b_ih, b_hh, F1T, fc1_b, F2T, fc2_b, out_s, out_h);
        return;
    }

    // ---- fallback: round-11 verified multi-launch path ----
    float* hA   = (float*)d_ws;
    float* hB   = hA + BB * HH;
    float* aBuf = hB + BB * HH;
    float* sBuf = aBuf + BB * HH;
    const dim3 blk(256);
    const dim3 gruGrid(HH / 4, BB / 64);
    const float* hcur = nullptr;
    for (int t = 0; t < TT; ++t) {
        float* hout = (t & 1) ? hB : hA;
        float* hout2 = (t == TT - 1) ? out_h : nullptr;
        gru_step_wj<<<gruGrid, blk, 0, stream>>>(state_seq + t * DD, TT * DD, hcur,
                                                 W_ih, W_hh, b_ih, b_hh,
                                                 hout, hout2, FF * HH);
        hcur = hout;
    }
    for (int t = 0; t < FF; ++t) {
        fc1_relu<<<dim3(HH / 32, BB / 16), blk, 0, stream>>>(hcur, fc1_w, fc1_b, aBuf);
        fc2_out<<<dim3(BB / 4), blk, 0, stream>>>(aBuf, fc2_w, fc2_b, sBuf,
                                                  out_s + t * DD, FF * DD);
        if (t < FF - 1) {
            float* hout = (hcur == hA) ? hB : hA;
            gru_step_wj<<<gruGrid, blk, 0, stream>>>(sBuf, DD, hcur,
                                                     W_ih, W_hh, b_ih, b_hh,
                                                     hout, out_h + (t + 1) * HH, FF * HH);
            hcur = hout;
        }
    }
}

// Round 13
// 34323.389 us; speedup vs baseline: 2.4371x; 2.4371x over previous
//
#include <hip/hip_runtime.h>
#include <hip/hip_cooperative_groups.h>
#include <math.h>

namespace cg = cooperative_groups;

#define BB 256   // batch
#define TT 512   // encoder seq len
#define DD 64    // state dim
#define HH 512   // hidden dim
#define FF 32    // fc_seq_len (decoder steps)
#define NWG 256
#define THR 256
#define SLOTP 16          // barrier slot padding (ints) -> 64 B/slot

__device__ __forceinline__ float sigmoidf_(float x) { return 1.0f / (1.0f + __expf(-x)); }

// ---------------- weight-stationary persistent kernel (atomic-spin edition) --
// wg w: jt = w>>2 (64 j-tiles of 8 cols), g = w&3 (4 batch groups of 64 rows).
// 256 threads: jj = tid>>5 (0..7), bi = tid&31, q in {0,1}: b = b0+bi+32q.
// GRU weights for the wg's 8 j-cols stay in LDS for all 543 steps.
// Sync: ONE cg grid.sync after barrier-slot init (round-8-proven), then
// group-local spin barriers built from atomicAdd/atomicExch + __threadfence
// (device-scope coherent cross-XCD per guide G12) — none of the constructs
// from the r5-r7 crash rounds (__hip_atomic_*, __syncthreads_and, s_sleep).
struct SmemG {
    float w[3][8][578];    // gate weights, cols 0..63 = W_ih, 64..575 = W_hh
    float hbuf[64][34];    // staged x/h tile; stride 34 -> 2-way alias (free)
    float wfc1[8][34];     // fc1 weight tile
};
struct SmemF2 {
    float w[3][8][578];
    float ws2[64][34];     // fc2 weights (64 rows)
    float as2[4][34];      // fc1 activations (4 rows)
};
union SmemU { SmemG g; SmemF2 f2; };   // 65280 B

// arrive: all wg work done + visible, then publish sid in own slot.
__device__ __forceinline__ void bar_arrive(int* bar, int slot16, int sid) {
    __syncthreads();
    __threadfence();
    if (threadIdx.x == 0) atomicExch(&bar[slot16], sid);
}
// wait: 64 lanes poll the 64 slots of this group; others park at syncthreads.
__device__ __forceinline__ void bar_wait(int* bar, int gbase16, int sid) {
    if (threadIdx.x < 64) {
        while (atomicAdd(&bar[gbase16 + (int)threadIdx.x * SLOTP], 0) < sid) { }
    }
    __syncthreads();
    __threadfence();
}

// stage 64 rows x 32 cols of src (row stride rs) into hbuf-shaped LDS.
__device__ __forceinline__ void stage_issue(float2* pre, const float* __restrict__ src,
                                            int rs, int kc, int b0, int tid) {
    #pragma unroll
    for (int i = 0; i < 4; ++i)
        pre[i] = *(const float2*)&src[(b0 + i * 16 + (tid >> 4)) * rs + kc + (tid & 15) * 2];
}
__device__ __forceinline__ void stage_commit(float (*buf)[34], const float2* pre, int tid) {
    #pragma unroll
    for (int i = 0; i < 4; ++i)
        *(float2*)&buf[i * 16 + (tid >> 4)][(tid & 15) * 2] = pre[i];
}

// one 32-K chunk of the 3 gate GEMMs: 5 ds_read_b64 / 12 FMA per k-pair
__device__ __forceinline__ void gru_chunk(const SmemG& g, int jj, int bi, int kb,
                                          float* ar, float* az, float* an) {
    #pragma unroll
    for (int kk = 0; kk < 32; kk += 2) {
        const float2 w0 = *(const float2*)&g.w[0][jj][kb + kk];
        const float2 w1 = *(const float2*)&g.w[1][jj][kb + kk];
        const float2 w2 = *(const float2*)&g.w[2][jj][kb + kk];
        #pragma unroll
        for (int q = 0; q < 2; ++q) {
            const float2 hv = *(const float2*)&g.hbuf[bi + 32 * q][kk];
            ar[q] = fmaf(hv.x, w0.x, ar[q]); ar[q] = fmaf(hv.y, w0.y, ar[q]);
            az[q] = fmaf(hv.x, w1.x, az[q]); az[q] = fmaf(hv.y, w1.y, az[q]);
            an[q] = fmaf(hv.x, w2.x, an[q]); an[q] = fmaf(hv.y, w2.y, an[q]);
        }
    }
}

// One GRU step for this wg's [64 batch x 8 j] tile.
// wsid >= 0: before the h-part, wait until all wgs of this group arrived wsid.
__device__ void gru_step_ws(SmemU& sm, int* bar, int gbase16, int wsid,
                            int tid, int jj, int bi, int b0, int j,
                            const float* __restrict__ x, int xs,
                            const float* __restrict__ hprev,
                            float br, float bz, float bin, float bhn,
                            float* __restrict__ hnew,
                            float* __restrict__ h2, int h2s) {
    float ar[2] = {0,0}, az[2] = {0,0}, ain[2] = {0,0}, ahn[2] = {0,0};
    float2 pre[4];

    // ---- x part: K 0..63 (weight cols 0..63); no cross-wg dependency ----
    stage_issue(pre, x, xs, 0, b0, tid);
    stage_commit(sm.g.hbuf, pre, tid);
    __syncthreads();
    stage_issue(pre, x, xs, 32, b0, tid);
    gru_chunk(sm.g, jj, bi, 0, ar, az, ain);
    __syncthreads();
    stage_commit(sm.g.hbuf, pre, tid);
    __syncthreads();
    gru_chunk(sm.g, jj, bi, 32, ar, az, ain);
    __syncthreads();

    if (wsid >= 0) bar_wait(bar, gbase16, wsid);   // h(t-1) of this group ready

    // ---- h part: K 0..511 (weight cols 64..575) ----
    if (hprev) {
        stage_issue(pre, hprev, HH, 0, b0, tid);
        stage_commit(sm.g.hbuf, pre, tid);
        __syncthreads();
        for (int c = 0; c < 16; ++c) {
            if (c < 15) stage_issue(pre, hprev, HH, 32 * (c + 1), b0, tid);
            gru_chunk(sm.g, jj, bi, 64 + 32 * c, ar, az, ahn);
            __syncthreads();
            if (c < 15) { stage_commit(sm.g.hbuf, pre, tid); __syncthreads(); }
        }
    }

    // ---- epilogue: n = tanh(i_n + r*h_n); h' = (1-z)n + z h ----
    #pragma unroll
    for (int q = 0; q < 2; ++q) {
        const int b = b0 + bi + 32 * q;
        const float r = sigmoidf_(ar[q] + br);
        const float z = sigmoidf_(az[q] + bz);
        const float hold = hprev ? hprev[b * HH + j] : 0.f;
        const float n = tanhf(ain[q] + bin + r * (ahn[q] + bhn));
        const float hn = (1.f - z) * n + z * hold;
        hnew[b * HH + j] = hn;
        if (h2) h2[b * h2s + j] = hn;
    }
}

__device__ void fc1_ws(SmemU& sm, int tid, int jj, int bi, int b0, int j0, int j,
                       const float* __restrict__ hsrc,
                       const float* __restrict__ fc1_w, float fb1,
                       float* __restrict__ aBuf) {
    float acc[2] = {0, 0};
    float2 pre[4], prew;

    stage_issue(pre, hsrc, HH, 0, b0, tid);
    if (tid < 128) prew = *(const float2*)&fc1_w[(j0 + (tid >> 4)) * HH + (tid & 15) * 2];
    stage_commit(sm.g.hbuf, pre, tid);
    if (tid < 128) *(float2*)&sm.g.wfc1[tid >> 4][(tid & 15) * 2] = prew;
    __syncthreads();
    for (int c = 0; c < 16; ++c) {
        if (c < 15) {
            stage_issue(pre, hsrc, HH, 32 * (c + 1), b0, tid);
            if (tid < 128)
                prew = *(const float2*)&fc1_w[(j0 + (tid >> 4)) * HH + 32 * (c + 1) + (tid & 15) * 2];
        }
        #pragma unroll
        for (int kk = 0; kk < 32; kk += 2) {
            const float2 wv = *(const float2*)&sm.g.wfc1[jj][kk];
            #pragma unroll
            for (int q = 0; q < 2; ++q) {
                const float2 hv = *(const float2*)&sm.g.hbuf[bi + 32 * q][kk];
                acc[q] = fmaf(hv.x, wv.x, acc[q]); acc[q] = fmaf(hv.y, wv.y, acc[q]);
            }
        }
        __syncthreads();
        if (c < 15) {
            stage_commit(sm.g.hbuf, pre, tid);
            if (tid < 128) *(float2*)&sm.g.wfc1[tid >> 4][(tid & 15) * 2] = prew;
            __syncthreads();
        }
    }
    #pragma unroll
    for (int q = 0; q < 2; ++q)
        aBuf[(b0 + bi + 32 * q) * HH + j] = fmaxf(acc[q] + fb1, 0.f);
}

// fc2 (wgs with jt<16 only): 4 batch rows b0f..b0f+3, all 64 d.
__device__ void fc2_ws(SmemU& sm, int tid, int b0f, int t,
                       const float* __restrict__ aBuf,
                       const float* __restrict__ fc2_w, float fb2,
                       float* __restrict__ sBuf, float* __restrict__ out_s) {
    const int d = tid & 63, q4 = tid >> 6;
    float acc = 0.f;
    float2 pre[4], prea;

    stage_issue(pre, fc2_w, HH, 0, 0, tid);        // 64 rows of fc2_w
    if (tid < 64) prea = *(const float2*)&aBuf[(b0f + (tid >> 4)) * HH + (tid & 15) * 2];
    stage_commit(sm.f2.ws2, pre, tid);
    if (tid < 64) *(float2*)&sm.f2.as2[tid >> 4][(tid & 15) * 2] = prea;
    __syncthreads();
    for (int c = 0; c < 16; ++c) {
        if (c < 15) {
            stage_issue(pre, fc2_w, HH, 32 * (c + 1), 0, tid);
            if (tid < 64)
                prea = *(const float2*)&aBuf[(b0f + (tid >> 4)) * HH + 32 * (c + 1) + (tid & 15) * 2];
        }
        #pragma unroll
        for (int kk = 0; kk < 32; kk += 2) {
            const float2 wv = *(const float2*)&sm.f2.ws2[d][kk];
            const float2 av = *(const float2*)&sm.f2.as2[q4][kk];
            acc = fmaf(av.x, wv.x, acc); acc = fmaf(av.y, wv.y, acc);
        }
        __syncthreads();
        if (c < 15) {
            stage_commit(sm.f2.ws2, pre, tid);
            if (tid < 64) *(float2*)&sm.f2.as2[tid >> 4][(tid & 15) * 2] = prea;
            __syncthreads();
        }
    }
    const float v = acc + fb2;
    const int b = b0f + q4;
    sBuf[b * DD + d] = v;
    out_s[b * (FF * DD) + t * DD + d] = v;
}

__global__ void __launch_bounds__(THR) gru_ws_persistent(
    const float* __restrict__ state_seq,
    const float* __restrict__ W_ih, const float* __restrict__ W_hh,
    const float* __restrict__ b_ih, const float* __restrict__ b_hh,
    const float* __restrict__ fc1_w, const float* __restrict__ fc1_b,
    const float* __restrict__ fc2_w, const float* __restrict__ fc2_b,
    float* __restrict__ out_s, float* __restrict__ out_h,
    float* __restrict__ hA, float* __restrict__ hB,
    float* __restrict__ aBuf, float* __restrict__ sBuf, int* bar) {
    __shared__ SmemU sm;
    const int tid = threadIdx.x;
    const int w = blockIdx.x;
    const int jt = w >> 2, g = w & 3;
    const int j0 = jt * 8, b0 = g * 64;
    const int jj = tid >> 5, bi = tid & 31;
    const int j = j0 + jj;
    const int gbase16 = g * 64 * SLOTP;
    const int slot16  = gbase16 + jt * SLOTP;

    // ---- barrier init: zero own slot; fence with the ONE cg grid sync ----
    if (tid == 0) bar[slot16] = 0;
    cg::this_grid().sync();

    // one-time: this wg's GRU weight slice into LDS (cols 0..63 = W_ih)
    for (int i = tid; i < 3 * 8 * 576; i += THR) {
        const int gg = i / 4608, rem = i - gg * 4608, r = rem / 576, k = rem - r * 576;
        sm.g.w[gg][r][k] = (k < DD) ? W_ih[(gg * HH + j0 + r) * DD + k]
                                    : W_hh[(gg * HH + j0 + r) * HH + (k - DD)];
    }
    const float br  = b_ih[j] + b_hh[j];
    const float bz  = b_ih[HH + j] + b_hh[HH + j];
    const float bin = b_ih[2 * HH + j];
    const float bhn = b_hh[2 * HH + j];
    const float fb1 = fc1_b[j];
    const float fb2 = (jt < 16) ? fc2_b[tid & 63] : 0.f;
    __syncthreads();

    int sid = 0;
    const float* hprev = nullptr;

    // ---- encoder: 512 steps ----
    for (int t = 0; t < TT; ++t) {
        float* hnew = (t & 1) ? hB : hA;
        gru_step_ws(sm, bar, gbase16, (t > 0) ? sid : -1, tid, jj, bi, b0, j,
                    state_seq + t * DD, TT * DD, hprev, br, bz, bin, bhn,
                    hnew, (t == TT - 1) ? out_h : nullptr, FF * HH);
        ++sid; bar_arrive(bar, slot16, sid);
        hprev = hnew;
    }

    // ---- decoder: 32 fc_predicts, 31 GRU steps ----
    for (int t = 0; t < FF; ++t) {
        bar_wait(bar, gbase16, sid);               // h(t) complete (this group)
        fc1_ws(sm, tid, jj, bi, b0, j0, j, hprev, fc1_w, fb1, aBuf);
        ++sid; bar_arrive(bar, slot16, sid);

        if (jt < 16) {
            bar_wait(bar, gbase16, sid);           // aBuf complete
            fc2_ws(sm, tid, b0 + jt * 4, t, aBuf, fc2_w, fb2, sBuf, out_s);
        }
        ++sid; bar_arrive(bar, slot16, sid);

        if (t < FF - 1) {
            bar_wait(bar, gbase16, sid);           // sBuf complete
            float* hnew = ((TT + t) & 1) ? hB : hA;
            gru_step_ws(sm, bar, gbase16, -1, tid, jj, bi, b0, j, sBuf, DD, hprev,
                        br, bz, bin, bhn, hnew, out_h + (t + 1) * HH, FF * HH);
            ++sid; bar_arrive(bar, slot16, sid);
            hprev = hnew;
        }
    }
}

// ---------------- fallback per-step kernels (round-3-verified) ----------------
struct SmemOld { float hs[16][34]; float ws[96][34]; };
#define GRU_TILE_LOOP(N0, N1)                                              \
    _Pragma("unroll")                                                      \
    for (int k = 0; k < 32; k += 2) {                                      \
        const float2 a0 = *(const float2*)&hs[bb][k];                      \
        const float2 a1 = *(const float2*)&hs[bb + 8][k];                  \
        const float2 w0 = *(const float2*)&ws[jj][k];                      \
        const float2 w1 = *(const float2*)&ws[32 + jj][k];                 \
        const float2 w2 = *(const float2*)&ws[64 + jj][k];                 \
        acc_r0 = fmaf(a0.x, w0.x, acc_r0); acc_r0 = fmaf(a0.y, w0.y, acc_r0); \
        acc_z0 = fmaf(a0.x, w1.x, acc_z0); acc_z0 = fmaf(a0.y, w1.y, acc_z0); \
        N0     = fmaf(a0.x, w2.x, N0);     N0     = fmaf(a0.y, w2.y, N0);     \
        acc_r1 = fmaf(a1.x, w0.x, acc_r1); acc_r1 = fmaf(a1.y, w0.y, acc_r1); \
        acc_z1 = fmaf(a1.x, w1.x, acc_z1); acc_z1 = fmaf(a1.y, w1.y, acc_z1); \
        N1     = fmaf(a1.x, w2.x, N1);     N1     = fmaf(a1.y, w2.y, N1);     \
    }

__global__ __launch_bounds__(256) void gru_step(
    const float* __restrict__ x, int x_stride, const float* __restrict__ h,
    const float* __restrict__ W_ih, const float* __restrict__ W_hh,
    const float* __restrict__ b_ih, const float* __restrict__ b_hh,
    float* __restrict__ h_out, float* __restrict__ h_out2, int h2s) {
    __shared__ SmemOld sm;
    float (*hs)[34] = sm.hs; float (*ws)[34] = sm.ws;
    const int tid = threadIdx.x;
    const int jj = tid & 31, bb = tid >> 5;
    const int j0 = blockIdx.x * 32, b0 = blockIdx.y * 16;
    float acc_r0 = 0.f, acc_z0 = 0.f, ghn0 = 0.f, gin0 = 0.f;
    float acc_r1 = 0.f, acc_z1 = 0.f, ghn1 = 0.f, gin1 = 0.f;
    for (int kt = 0; kt < DD; kt += 32) {
        { const int r = tid >> 4, c2 = (tid & 15) * 2;
          *(float2*)&hs[r][c2] = *(const float2*)&x[(b0 + r) * x_stride + kt + c2]; }
        #pragma unroll
        for (int i = 0; i < 6; ++i) {
            const int idx = i * 256 + tid, r = idx >> 4, c2 = (idx & 15) * 2;
            const int row = (r >> 5) * HH + j0 + (r & 31);
            *(float2*)&ws[r][c2] = *(const float2*)&W_ih[row * DD + kt + c2];
        }
        __syncthreads(); GRU_TILE_LOOP(gin0, gin1) __syncthreads();
    }
    if (h != nullptr) {
        for (int kt = 0; kt < HH; kt += 32) {
            { const int r = tid >> 4, c2 = (tid & 15) * 2;
              *(float2*)&hs[r][c2] = *(const float2*)&h[(b0 + r) * HH + kt + c2]; }
            #pragma unroll
            for (int i = 0; i < 6; ++i) {
                const int idx = i * 256 + tid, r = idx >> 4, c2 = (idx & 15) * 2;
                const int row = (r >> 5) * HH + j0 + (r & 31);
                *(float2*)&ws[r][c2] = *(const float2*)&W_hh[row * HH + kt + c2];
            }
            __syncthreads(); GRU_TILE_LOOP(ghn0, ghn1) __syncthreads();
        }
    }
    const int j = j0 + jj;
    const float br = b_ih[j] + b_hh[j], bz = b_ih[HH + j] + b_hh[HH + j];
    const float bin = b_ih[2 * HH + j], bhn = b_hh[2 * HH + j];
    { const int b = b0 + bb;
      const float r = sigmoidf_(acc_r0 + br), z = sigmoidf_(acc_z0 + bz);
      const float hold = h ? h[b * HH + j] : 0.f;
      const float n = tanhf(gin0 + bin + r * (ghn0 + bhn));
      const float hn = (1.f - z) * n + z * hold;
      h_out[b * HH + j] = hn; if (h_out2) h_out2[b * h2s + j] = hn; }
    { const int b = b0 + bb + 8;
      const float r = sigmoidf_(acc_r1 + br), z = sigmoidf_(acc_z1 + bz);
      const float hold = h ? h[b * HH + j] : 0.f;
      const float n = tanhf(gin1 + bin + r * (ghn1 + bhn));
      const float hn = (1.f - z) * n + z * hold;
      h_out[b * HH + j] = hn; if (h_out2) h_out2[b * h2s + j] = hn; }
}

__global__ __launch_bounds__(256) void fc1_relu(
    const float* __restrict__ h, const float* __restrict__ wsrc,
    const float* __restrict__ bias, float* __restrict__ out) {
    __shared__ SmemOld sm;
    float (*hs)[34] = sm.hs; float (*ws)[34] = sm.ws;
    const int tid = threadIdx.x;
    const int jj = tid & 31, bb = tid >> 5;
    const int j0 = blockIdx.x * 32, b0 = blockIdx.y * 16;
    float a0 = 0.f, a1 = 0.f;
    for (int kt = 0; kt < HH; kt += 32) {
        { const int r = tid >> 4, c2 = (tid & 15) * 2;
          *(float2*)&hs[r][c2] = *(const float2*)&h[(b0 + r) * HH + kt + c2]; }
        #pragma unroll
        for (int i = 0; i < 2; ++i) {
            const int idx = i * 256 + tid, r = idx >> 4, c2 = (idx & 15) * 2;
            *(float2*)&ws[r][c2] = *(const float2*)&wsrc[(j0 + r) * HH + kt + c2];
        }
        __syncthreads();
        #pragma unroll
        for (int k = 0; k < 32; k += 2) {
            const float2 h0 = *(const float2*)&hs[bb][k];
            const float2 h1 = *(const float2*)&hs[bb + 8][k];
            const float2 w0 = *(const float2*)&ws[jj][k];
            a0 = fmaf(h0.x, w0.x, a0); a0 = fmaf(h0.y, w0.y, a0);
            a1 = fmaf(h1.x, w0.x, a1); a1 = fmaf(h1.y, w0.y, a1);
        }
        __syncthreads();
    }
    const float b = bias[j0 + jj];
    out[(b0 + bb) * HH + j0 + jj]     = fmaxf(a0 + b, 0.f);
    out[(b0 + bb + 8) * HH + j0 + jj] = fmaxf(a1 + b, 0.f);
}

__global__ __launch_bounds__(256) void fc2_out(
    const float* __restrict__ a, const float* __restrict__ wsrc,
    const float* __restrict__ bias, float* __restrict__ s_buf,
    float* __restrict__ s_out, int s_stride) {
    __shared__ SmemOld sm;
    float (*as)[34] = sm.hs; float (*ws)[34] = sm.ws;
    const int tid = threadIdx.x;
    const int d = tid & 63, bb = tid >> 6;
    const int b0 = blockIdx.x * 4;
    float acc = 0.f;
    for (int kt = 0; kt < HH; kt += 32) {
        if (tid < 64) { const int r = tid >> 4, c2 = (tid & 15) * 2;
            *(float2*)&as[r][c2] = *(const float2*)&a[(b0 + r) * HH + kt + c2]; }
        #pragma unroll
        for (int i = 0; i < 4; ++i) {
            const int idx = i * 256 + tid, r = idx >> 4, c2 = (idx & 15) * 2;
            *(float2*)&ws[r][c2] = *(const float2*)&wsrc[r * HH + kt + c2];
        }
        __syncthreads();
        #pragma unroll
        for (int k = 0; k < 32; k += 2) {
            const float2 av = *(const float2*)&as[bb][k];
            const float2 wv = *(const float2*)&ws[d][k];
            acc = fmaf(av.x, wv.x, acc); acc = fmaf(av.y, wv.y, acc);
        }
        __syncthreads();
    }
    const float v = acc + bias[d];
    s_buf[(b0 + bb) * DD + d] = v;
    s_out[(b0 + bb) * s_stride + d] = v;
}

extern "C" void kernel_launch(void* const* d_in, const int* in_sizes, int n_in,
                              void* d_out, int out_size, void* d_ws, size_t ws_size,
                              hipStream_t stream) {
    const float* state_seq = (const float*)d_in[0];
    const float* W_ih  = (const float*)d_in[1];
    const float* W_hh  = (const float*)d_in[2];
    const float* b_ih  = (const float*)d_in[3];
    const float* b_hh  = (const float*)d_in[4];
    const float* fc1_w = (const float*)d_in[5];
    const float* fc1_b = (const float*)d_in[6];
    const float* fc2_w = (const float*)d_in[7];
    const float* fc2_b = (const float*)d_in[8];

    float* out_s = (float*)d_out;                 // [256, 32, 64]
    float* out_h = out_s + BB * FF * DD;          // [256, 32, 512]

    float* hA   = (float*)d_ws;
    float* hB   = hA + BB * HH;
    float* aBuf = hB + BB * HH;
    float* sBuf = aBuf + BB * HH;
    int*   bar  = (int*)(sBuf + BB * DD);
    const size_t need = (size_t)(3 * BB * HH + BB * DD) * 4 + (size_t)NWG * SLOTP * 4;

    bool coop_ok = false;
    if (ws_size >= need) {
        // SINGLE graph node (round-4/8-proven capture shape).
        void* args[] = {
            (void*)&state_seq, (void*)&W_ih, (void*)&W_hh, (void*)&b_ih, (void*)&b_hh,
            (void*)&fc1_w, (void*)&fc1_b, (void*)&fc2_w, (void*)&fc2_b,
            (void*)&out_s, (void*)&out_h, (void*)&hA, (void*)&hB,
            (void*)&aBuf, (void*)&sBuf, (void*)&bar };
        hipError_t e = hipLaunchCooperativeKernel((const void*)gru_ws_persistent,
                                                  dim3(NWG), dim3(THR), args, 0, stream);
        coop_ok = (e == hipSuccess);
        if (!coop_ok) (void)hipGetLastError();
    }
    if (coop_ok) return;

    // fallback: verified per-step path
    const dim3 blk(256);
    const dim3 gruGrid(HH / 32, BB / 16);
    const float* hcur = nullptr;
    for (int t = 0; t < TT; ++t) {
        float* hout = (t & 1) ? hB : hA;
        float* hout2 = (t == TT - 1) ? out_h : nullptr;
        gru_step<<<gruGrid, blk, 0, stream>>>(state_seq + t * DD, TT * DD, hcur,
                                              W_ih, W_hh, b_ih, b_hh, hout, hout2, FF * HH);
        hcur = hout;
    }
    for (int t = 0; t < FF; ++t) {
        fc1_relu<<<dim3(HH / 32, BB / 16), blk, 0, stream>>>(hcur, fc1_w, fc1_b, aBuf);
        fc2_out<<<dim3(BB / 4), blk, 0, stream>>>(aBuf, fc2_w, fc2_b, sBuf,
                                                  out_s + t * DD, FF * DD);
        if (t < FF - 1) {
            float* hout = (hcur == hA) ? hB : hA;
            gru_step<<<gruGrid, blk, 0, stream>>>(sBuf, DD, hcur, W_ih, W_hh, b_ih, b_hh,
                                                  hout, out_h + (t + 1) * HH, FF * HH);
            hcur = hout;
        }
    }
}